// Round 7
// baseline (569.958 us; speedup 1.0000x reference)
//
#include <hip/hip_runtime.h>

// Problem: B=16, T=4096, D=512, R=256. Output (B,T,R+1) FLOAT32 (ref dtype).
// Block = one batch b and 8 consecutive t-rows; 256 threads; thread tid owns
// landmark column r = tid. All math f32. K rows are L2-resident (512 KB/batch).

__global__ void NystromCausalBasis_42090679501208_kernel(
        const float* z, const float* gw, const float* ta,
        const void* lms_raw, float* out) {
    __shared__ __align__(16) float q[8][512];   // staged Q rows, 16 KB
    __shared__ float red[8][256];               // reduction scratch, 8 KB
    __shared__ float s_inv[8];                  // 1 / ||q_j||
    __shared__ float s_rsi[8];                  // 1 / row_sum

    const int T = 4096;
    const int D = 512;
    const int R = 256;

    int tid = threadIdx.x;
    int bpb = T / 8;                            // 512 row-groups per batch
    int b   = blockIdx.x / bpb;
    int t0  = (blockIdx.x - b * bpb) * 8;

    // landmarks: probe int32 vs int64 layout (linspace(0,4095,256):
    // int32 -> l32[1]==16 ; int64 little-endian -> l32[1]==0).
    const int* l32 = (const int*)lms_raw;
    int lm;
    if (l32[1] == 0) {
        const long long* l64 = (const long long*)lms_raw;
        lm = (int)l64[tid];
    } else {
        lm = l32[tid];
    }

    // scalars: softmax(gw), softplus(ta)
    float w0 = gw[0], w1 = gw[1], w2 = gw[2];
    float wm = fmaxf(w0, fmaxf(w1, w2));
    float e0 = expf(w0 - wm), e1 = expf(w1 - wm), e2 = expf(w2 - wm);
    float einv = 1.0f / (e0 + e1 + e2);
    float sa0 = e0 * einv, sa1 = e1 * einv, sa2 = e2 * einv;
    float tv = ta[0];
    float atd;
    if (tv > 0.0f) atd = tv + log1pf(expf(-tv));
    else           atd = log1pf(expf(tv));

    // stage 8 Q rows into LDS (float4) + squared-norm partials
    {
        int part = tid & 31;                    // 32 lanes per row-group
        int jrow = tid >> 5;                    // 8 groups -> 8 rows
        const float* zr = z + ((size_t)b * T + (size_t)(t0 + jrow)) * D;
        const float4* zr4 = (const float4*)zr;
        float4* q4 = (float4*)q[jrow];
        float ss = 0.0f;
        for (int i = part; i < D / 4; i += 32) {
            float4 v = zr4[i];
            q4[i] = v;
            ss = fmaf(v.x, v.x, fmaf(v.y, v.y, fmaf(v.z, v.z, fmaf(v.w, v.w, ss))));
        }
        red[jrow][part] = ss;
    }
    __syncthreads();
    if (tid < 8) {
        float s = 0.0f;
        for (int i = 0; i < 32; ++i) s += red[tid][i];
        s_inv[tid] = 1.0f / fmaxf(sqrtf(s), 1e-12f);
    }
    __syncthreads();

    // dot(q_j, K_r) for all 8 rows + ||K_r||, streaming K_r once (float4)
    const float4* kr = (const float4*)(z + ((size_t)b * T + (size_t)lm) * D);
    float accv[8];
    #pragma unroll
    for (int j = 0; j < 8; ++j) accv[j] = 0.0f;
    float kss = 0.0f;
    for (int k = 0; k < D / 4; ++k) {
        float4 kv = kr[k];
        kss = fmaf(kv.x, kv.x, fmaf(kv.y, kv.y, fmaf(kv.z, kv.z, fmaf(kv.w, kv.w, kss))));
        #pragma unroll
        for (int j = 0; j < 8; ++j) {
            float4 qv = ((const float4*)q[j])[k];   // wave-broadcast LDS read
            accv[j] = fmaf(qv.x, kv.x, fmaf(qv.y, kv.y,
                       fmaf(qv.z, kv.z, fmaf(qv.w, kv.w, accv[j]))));
        }
    }
    float kinv = 1.0f / fmaxf(sqrtf(kss), 1e-12f);

    // epilogue: causal mask, Gegenbauer polys, temporal decay
    float phiv[8];
    #pragma unroll
    for (int j = 0; j < 8; ++j) {
        int tg = t0 + j;
        float cv = 0.0f;
        if (lm < tg) cv = accv[j] * s_inv[j] * kinv;
        float c2 = cv * cv;
        float p1 = 0.5f * (1.0f + cv);
        float p2 = 0.5f * (3.0f * c2 - 1.0f);
        float p3 = 0.5f * (5.0f * c2 * cv - 3.0f * cv);
        float ph = sa0 * p1 + sa1 * p2 + sa2 * p3;
        float dist = 0.0f;
        if (lm < tg) dist = (float)(tg - lm) / (float)T;
        ph = ph * expf(-atd * dist);
        phiv[j] = ph;
        red[j][tid] = ph;
    }
    __syncthreads();
    for (int s = 128; s >= 1; s >>= 1) {
        if (tid < s) {
            for (int j = 0; j < 8; ++j) red[j][tid] += red[j][tid + s];
        }
        __syncthreads();
    }
    if (tid < 8) s_rsi[tid] = 1.0f / fmaxf(red[tid][0], 1e-6f);
    __syncthreads();

    // normalize + f32 store, plus ones column
    for (int j = 0; j < 8; ++j) {
        size_t base = ((size_t)b * T + (size_t)(t0 + j)) * (size_t)(R + 1);
        out[base + tid] = phiv[j] * s_rsi[j];
    }
    if (tid < 8) {
        size_t base = ((size_t)b * T + (size_t)(t0 + tid)) * (size_t)(R + 1);
        out[base + R] = 1.0f;
    }
}

extern "C" void kernel_launch(void* const* d_in, const int* in_sizes, int n_in,
                              void* d_out, int out_size, void* d_ws, size_t ws_size,
                              hipStream_t stream) {
    const float* z   = (const float*)d_in[0];
    const float* gw  = (const float*)d_in[1];
    const float* ta  = (const float*)d_in[2];
    const void*  lms = (const void*)d_in[3];
    float* out = (float*)d_out;

    int blocks = 16 * (4096 / 8);    // 8192
    NystromCausalBasis_42090679501208_kernel<<<blocks, 256, 0, stream>>>(
        z, gw, ta, lms, out);
}

// Round 8
// 88.506 us; speedup vs baseline: 6.4397x; 6.4397x over previous
//
#include <hip/hip_runtime.h>

// Problem: B=16, T=4096, D=512, R=256. Output (B,T,R+1) float32.
// Pipeline: build_kt writes a normalized bf16 K panel to d_ws; nystrom_mfma
// computes C = Q * K^T via mfma_f32_16x16x32_bf16 and fuses the epilogue.

typedef float f32x4 __attribute__((ext_vector_type(4)));
typedef short s16x8 __attribute__((ext_vector_type(8)));
typedef unsigned short u16x4 __attribute__((ext_vector_type(4)));
typedef unsigned short u16x8 __attribute__((ext_vector_type(8)));

// float -> bf16 bits, round-to-nearest-even (finite values only)
__device__ __forceinline__ unsigned short f2bf(float f) {
    unsigned u = __builtin_bit_cast(unsigned, f);
    return (unsigned short)((u + 0x7FFFu + ((u >> 16) & 1u)) >> 16);
}

// landmarks: probe int32 vs int64 layout. linspace(0,4095,256):
// int32 -> word1 == 16 ; int64 little-endian -> word1 (high half of elt 0) == 0.
__device__ __forceinline__ int load_lm(const void* lms_raw, int idx) {
    const int* l32 = (const int*)lms_raw;
    if (l32[1] == 0) {
        const long long* l64 = (const long long*)lms_raw;
        return (int)l64[idx];
    }
    return l32[idx];
}

// softmax(gw) and softplus(ta)
__device__ __forceinline__ void scalars(const float* gw, const float* ta,
                                        float& a0, float& a1, float& a2, float& atd) {
    float w0 = gw[0], w1 = gw[1], w2 = gw[2];
    float wm = fmaxf(w0, fmaxf(w1, w2));
    float e0 = __expf(w0 - wm), e1 = __expf(w1 - wm), e2 = __expf(w2 - wm);
    float einv = 1.0f / (e0 + e1 + e2);
    a0 = e0 * einv; a1 = e1 * einv; a2 = e2 * einv;
    float tv = ta[0];
    atd = (tv > 0.0f) ? (tv + log1pf(__expf(-tv))) : log1pf(__expf(tv));
}

// ---------------------------------------------------------------------------
// Kernel 1: normalized K panel, bf16 row-major: kb[(b*256 + r)*512 + k].
// One wave per (b, r). 16 * 256 rows total.
// ---------------------------------------------------------------------------
__global__ void build_kt(const float* __restrict__ z,
                         const void* __restrict__ lms_raw,
                         unsigned short* __restrict__ kb) {
    const int b    = blockIdx.x >> 8;
    const int r    = blockIdx.x & 255;
    const int lane = threadIdx.x;
    const int lm   = load_lm(lms_raw, r);

    const f32x4* zrow = (const f32x4*)(z + ((size_t)b * 4096 + (size_t)lm) * 512);
    f32x4 v0 = zrow[lane * 2 + 0];
    f32x4 v1 = zrow[lane * 2 + 1];
    float ss = v0.x*v0.x + v0.y*v0.y + v0.z*v0.z + v0.w*v0.w
             + v1.x*v1.x + v1.y*v1.y + v1.z*v1.z + v1.w*v1.w;
    #pragma unroll
    for (int off = 32; off >= 1; off >>= 1) ss += __shfl_xor(ss, off, 64);
    float inv = 1.0f / fmaxf(sqrtf(ss), 1e-12f);

    u16x8 o;
    o[0]=f2bf(v0.x*inv); o[1]=f2bf(v0.y*inv); o[2]=f2bf(v0.z*inv); o[3]=f2bf(v0.w*inv);
    o[4]=f2bf(v1.x*inv); o[5]=f2bf(v1.y*inv); o[6]=f2bf(v1.z*inv); o[7]=f2bf(v1.w*inv);
    *(u16x8*)(kb + ((size_t)b * 256 + (size_t)r) * 512 + lane * 8) = o;
}

// ---------------------------------------------------------------------------
// Kernel 2: MFMA main. Block = (b, 32 t-rows) x 256 r; 4 waves, wave w owns
// r in [64w, 64w+64). mfma_f32_16x16x32_bf16:
//   A frag: row = lane&15, k = (lane>>4)*8 + j   (same k-map used for B ->
//   inner product invariant to any consistent HW k-permutation)
//   C/D: col = lane&15, row = (lane>>4)*4 + reg  [HW-verified]
// ---------------------------------------------------------------------------
__global__ __launch_bounds__(256) void nystrom_mfma(const float* __restrict__ z,
                                                    const float* __restrict__ gw,
                                                    const float* __restrict__ ta,
                                                    const void* __restrict__ lms_raw,
                                                    const unsigned short* __restrict__ kb,
                                                    float* __restrict__ out) {
    __shared__ unsigned char qtile[32 * 512 * 2];  // 32 KB swizzled bf16 Q tile
    __shared__ float s_invn[32];
    __shared__ float s_rs[4][32];
    __shared__ float s_rsi[32];

    const int tid  = threadIdx.x;
    const int lane = tid & 63;
    const int w    = tid >> 6;                 // wave 0..3
    const int b    = blockIdx.x >> 7;          // 128 blocks per batch
    const int t0   = (blockIdx.x & 127) * 32;

    float sa0, sa1, sa2, alpha_td;
    scalars(gw, ta, sa0, sa1, sa2, alpha_td);
    const float C0 = 0.5f * (sa0 - sa1);       // Phi at masked positions (C=0, dist=0)

    // --- stage z -> bf16 LDS (XOR swizzle: byte ^= (row&7)<<4) + row norms ---
    {
        const int row = tid >> 3, part = tid & 7;
        const f32x4* zr = (const f32x4*)(z + ((size_t)b * 4096 + (size_t)(t0 + row)) * 512);
        float ss = 0.0f;
        #pragma unroll
        for (int i = 0; i < 16; ++i) {
            f32x4 v = zr[part + 8 * i];
            ss += v.x*v.x + v.y*v.y + v.z*v.z + v.w*v.w;
            u16x4 h; h[0]=f2bf(v.x); h[1]=f2bf(v.y); h[2]=f2bf(v.z); h[3]=f2bf(v.w);
            int within = ((part + 8 * i) * 8) ^ ((row & 7) << 4);
            *(u16x4*)(qtile + row * 1024 + within) = h;
        }
        ss += __shfl_xor(ss, 1, 64);
        ss += __shfl_xor(ss, 2, 64);
        ss += __shfl_xor(ss, 4, 64);
        if (part == 0) s_invn[row] = 1.0f / fmaxf(sqrtf(ss), 1e-12f);
    }
    __syncthreads();

    const int c = lane & 15;   // fragment column
    const int g = lane >> 4;   // k-group / row-group

    f32x4 acc[2][4];
    #pragma unroll
    for (int tf = 0; tf < 2; ++tf)
        #pragma unroll
        for (int nf = 0; nf < 4; ++nf)
            acc[tf][nf] = 0.0f;

    // B straight from the L2-resident bf16 panel, per-lane 16B loads
    const unsigned short* kbb = kb + ((size_t)b * 256 + (size_t)(w * 64 + c)) * 512 + g * 8;
    const int swz = (c & 7) << 4;

    for (int ks = 0; ks < 16; ++ks) {
        u16x8 bu0 = *(const u16x8*)(kbb + 0 * 16 * 512 + ks * 32);
        u16x8 bu1 = *(const u16x8*)(kbb + 1 * 16 * 512 + ks * 32);
        u16x8 bu2 = *(const u16x8*)(kbb + 2 * 16 * 512 + ks * 32);
        u16x8 bu3 = *(const u16x8*)(kbb + 3 * 16 * 512 + ks * 32);
        int kw = (ks * 64 + g * 16) ^ swz;
        s16x8 a0f = *(const s16x8*)(qtile + c * 1024 + kw);
        s16x8 a1f = *(const s16x8*)(qtile + (c + 16) * 1024 + kw);
        s16x8 b0f = __builtin_bit_cast(s16x8, bu0);
        s16x8 b1f = __builtin_bit_cast(s16x8, bu1);
        s16x8 b2f = __builtin_bit_cast(s16x8, bu2);
        s16x8 b3f = __builtin_bit_cast(s16x8, bu3);
        acc[0][0] = __builtin_amdgcn_mfma_f32_16x16x32_bf16(a0f, b0f, acc[0][0], 0, 0, 0);
        acc[0][1] = __builtin_amdgcn_mfma_f32_16x16x32_bf16(a0f, b1f, acc[0][1], 0, 0, 0);
        acc[0][2] = __builtin_amdgcn_mfma_f32_16x16x32_bf16(a0f, b2f, acc[0][2], 0, 0, 0);
        acc[0][3] = __builtin_amdgcn_mfma_f32_16x16x32_bf16(a0f, b3f, acc[0][3], 0, 0, 0);
        acc[1][0] = __builtin_amdgcn_mfma_f32_16x16x32_bf16(a1f, b0f, acc[1][0], 0, 0, 0);
        acc[1][1] = __builtin_amdgcn_mfma_f32_16x16x32_bf16(a1f, b1f, acc[1][1], 0, 0, 0);
        acc[1][2] = __builtin_amdgcn_mfma_f32_16x16x32_bf16(a1f, b2f, acc[1][2], 0, 0, 0);
        acc[1][3] = __builtin_amdgcn_mfma_f32_16x16x32_bf16(a1f, b3f, acc[1][3], 0, 0, 0);
    }

    // --- epilogue ---
    int   lmv[4];
    float elm[4];
    #pragma unroll
    for (int nf = 0; nf < 4; ++nf) {
        int rr  = w * 64 + nf * 16 + c;
        lmv[nf] = load_lm(lms_raw, rr);
        elm[nf] = __expf(alpha_td * (float)lmv[nf] * (1.0f / 4096.0f));
    }
    float invn[2][4], et[2][4];
    #pragma unroll
    for (int tf = 0; tf < 2; ++tf)
        #pragma unroll
        for (int q = 0; q < 4; ++q) {
            int tl = tf * 16 + g * 4 + q;
            invn[tf][q] = s_invn[tl];
            et[tf][q]   = __expf(-alpha_td * (float)(t0 + tl) * (1.0f / 4096.0f));
        }

    float phi[2][4][4];
    float rsum[2][4];
    #pragma unroll
    for (int tf = 0; tf < 2; ++tf) {
        #pragma unroll
        for (int q = 0; q < 4; ++q) {
            int tg = t0 + tf * 16 + g * 4 + q;
            float s = 0.0f;
            #pragma unroll
            for (int nf = 0; nf < 4; ++nf) {
                float v = acc[tf][nf][q] * invn[tf][q];
                float p;
                if (lmv[nf] < tg) {
                    float c2 = v * v;
                    float p1 = fmaf(0.5f, v, 0.5f);          // (1+C)/2
                    float p2 = fmaf(1.5f, c2, -0.5f);        // (3C^2-1)/2
                    float p3 = v * fmaf(2.5f, c2, -1.5f);    // (5C^3-3C)/2
                    p = (sa0 * p1 + sa1 * p2 + sa2 * p3) * (et[tf][q] * elm[nf]);
                } else {
                    p = C0;
                }
                phi[tf][nf][q] = p;
                s += p;
            }
            rsum[tf][q] = s;
        }
    }

    // row sums: reduce across the 16 c-lanes, then across waves via LDS
    #pragma unroll
    for (int tf = 0; tf < 2; ++tf)
        #pragma unroll
        for (int q = 0; q < 4; ++q) {
            float s = rsum[tf][q];
            s += __shfl_xor(s, 1, 64);
            s += __shfl_xor(s, 2, 64);
            s += __shfl_xor(s, 4, 64);
            s += __shfl_xor(s, 8, 64);
            rsum[tf][q] = s;
        }
    if (c == 0) {
        #pragma unroll
        for (int tf = 0; tf < 2; ++tf)
            #pragma unroll
            for (int q = 0; q < 4; ++q)
                s_rs[w][tf * 16 + g * 4 + q] = rsum[tf][q];
    }
    __syncthreads();
    if (tid < 32) {
        float s = s_rs[0][tid] + s_rs[1][tid] + s_rs[2][tid] + s_rs[3][tid];
        s_rsi[tid] = 1.0f / fmaxf(s, 1e-6f);
    }
    __syncthreads();

    // normalize + f32 stores
    #pragma unroll
    for (int tf = 0; tf < 2; ++tf)
        #pragma unroll
        for (int q = 0; q < 4; ++q) {
            int tl = tf * 16 + g * 4 + q;
            float ri = s_rsi[tl];
            size_t obase = ((size_t)b * 4096 + (size_t)(t0 + tl)) * 257
                         + (size_t)(w * 64 + c);
            #pragma unroll
            for (int nf = 0; nf < 4; ++nf)
                out[obase + nf * 16] = phi[tf][nf][q] * ri;
        }
    if (tid < 32)
        out[((size_t)b * 4096 + (size_t)(t0 + tid)) * 257 + 256] = 1.0f;
}

// ---------------------------------------------------------------------------
extern "C" void kernel_launch(void* const* d_in, const int* in_sizes, int n_in,
                              void* d_out, int out_size, void* d_ws, size_t ws_size,
                              hipStream_t stream) {
    const float* z   = (const float*)d_in[0];
    const float* gw  = (const float*)d_in[1];
    const float* ta  = (const float*)d_in[2];
    const void*  lms = (const void*)d_in[3];
    float* out = (float*)d_out;
    unsigned short* kb = (unsigned short*)d_ws;   // 4 MB bf16 K panel

    build_kt<<<16 * 256, 64, 0, stream>>>(z, lms, kb);
    nystrom_mfma<<<16 * 128, 256, 0, stream>>>(z, gw, ta, lms, kb, out);
}

// Round 9
// 79.376 us; speedup vs baseline: 7.1804x; 1.1150x over previous
//
#include <hip/hip_runtime.h>

// Problem: B=16, T=4096, D=512, R=256. Output (B,T,R+1) float32.
// Pipeline: build_kt writes a normalized bf16 K panel to d_ws; nystrom_mfma
// computes C = Q * K^T via mfma_f32_16x16x32_bf16 and fuses the epilogue.

typedef float f32x4 __attribute__((ext_vector_type(4)));
typedef short s16x8 __attribute__((ext_vector_type(8)));
typedef unsigned short u16x4 __attribute__((ext_vector_type(4)));
typedef unsigned short u16x8 __attribute__((ext_vector_type(8)));

// float -> bf16 bits, round-to-nearest-even (finite values only)
__device__ __forceinline__ unsigned short f2bf(float f) {
    unsigned u = __builtin_bit_cast(unsigned, f);
    return (unsigned short)((u + 0x7FFFu + ((u >> 16) & 1u)) >> 16);
}

// landmarks: probe int32 vs int64 layout. linspace(0,4095,256):
// int32 -> word1 == 16 ; int64 little-endian -> word1 (high half of elt 0) == 0.
__device__ __forceinline__ int load_lm(const void* lms_raw, int idx) {
    const int* l32 = (const int*)lms_raw;
    if (l32[1] == 0) {
        const long long* l64 = (const long long*)lms_raw;
        return (int)l64[idx];
    }
    return l32[idx];
}

// softmax(gw) and softplus(ta)
__device__ __forceinline__ void scalars(const float* gw, const float* ta,
                                        float& a0, float& a1, float& a2, float& atd) {
    float w0 = gw[0], w1 = gw[1], w2 = gw[2];
    float wm = fmaxf(w0, fmaxf(w1, w2));
    float e0 = __expf(w0 - wm), e1 = __expf(w1 - wm), e2 = __expf(w2 - wm);
    float einv = 1.0f / (e0 + e1 + e2);
    a0 = e0 * einv; a1 = e1 * einv; a2 = e2 * einv;
    float tv = ta[0];
    atd = (tv > 0.0f) ? (tv + log1pf(__expf(-tv))) : log1pf(__expf(tv));
}

// ---------------------------------------------------------------------------
// Kernel 1: normalized K panel, bf16 row-major: kb[(b*256 + r)*512 + k].
// One wave per (b, r).
// ---------------------------------------------------------------------------
__global__ void build_kt(const float* __restrict__ z,
                         const void* __restrict__ lms_raw,
                         unsigned short* __restrict__ kb) {
    const int b    = blockIdx.x >> 8;
    const int r    = blockIdx.x & 255;
    const int lane = threadIdx.x;
    const int lm   = load_lm(lms_raw, r);

    const f32x4* zrow = (const f32x4*)(z + ((size_t)b * 4096 + (size_t)lm) * 512);
    f32x4 v0 = zrow[lane * 2 + 0];
    f32x4 v1 = zrow[lane * 2 + 1];
    float ss = v0.x*v0.x + v0.y*v0.y + v0.z*v0.z + v0.w*v0.w
             + v1.x*v1.x + v1.y*v1.y + v1.z*v1.z + v1.w*v1.w;
    #pragma unroll
    for (int off = 32; off >= 1; off >>= 1) ss += __shfl_xor(ss, off, 64);
    float inv = 1.0f / fmaxf(sqrtf(ss), 1e-12f);

    u16x8 o;
    o[0]=f2bf(v0.x*inv); o[1]=f2bf(v0.y*inv); o[2]=f2bf(v0.z*inv); o[3]=f2bf(v0.w*inv);
    o[4]=f2bf(v1.x*inv); o[5]=f2bf(v1.y*inv); o[6]=f2bf(v1.z*inv); o[7]=f2bf(v1.w*inv);
    *(u16x8*)(kb + ((size_t)b * 256 + (size_t)r) * 512 + lane * 8) = o;
}

// ---------------------------------------------------------------------------
// Kernel 2: MFMA main. Block = (b, 32 t-rows) x 256 r; 4 waves, wave w owns
// r in [64w, 64w+64). launch_bounds(256,4): LDS caps residency at 4 blocks/CU
// anyway, so allow the register allocator a deep pipeline (B prefetch x3).
// ---------------------------------------------------------------------------
__global__ __launch_bounds__(256, 4) void nystrom_mfma(const float* __restrict__ z,
                                                       const float* __restrict__ gw,
                                                       const float* __restrict__ ta,
                                                       const void* __restrict__ lms_raw,
                                                       const unsigned short* __restrict__ kb,
                                                       float* __restrict__ out) {
    __shared__ unsigned char qtile[32 * 512 * 2];  // 32 KB swizzled bf16 Q tile
    __shared__ float s_invn[32];
    __shared__ float s_rs[4][32];
    __shared__ float s_rsi[32];

    const int tid  = threadIdx.x;
    const int lane = tid & 63;
    const int w    = tid >> 6;                 // wave 0..3
    const int b    = blockIdx.x >> 7;          // 128 blocks per batch
    const int t0   = (blockIdx.x & 127) * 32;

    const int c = lane & 15;   // fragment column
    const int g = lane >> 4;   // k-group / row-group

    float sa0, sa1, sa2, alpha_td;
    scalars(gw, ta, sa0, sa1, sa2, alpha_td);
    const float C0 = 0.5f * (sa0 - sa1);       // Phi at masked positions (C=0, dist=0)

    // B-panel pointer; issue the first 3 K-step B-tiles NOW so their L2
    // latency hides under the whole staging phase.
    const unsigned short* kbb = kb + ((size_t)b * 256 + (size_t)(w * 64 + c)) * 512 + g * 8;
    u16x8 bbuf[3][4];
    #pragma unroll
    for (int p = 0; p < 3; ++p)
        #pragma unroll
        for (int nf = 0; nf < 4; ++nf)
            bbuf[p][nf] = *(const u16x8*)(kbb + nf * 16 * 512 + p * 32);

    // --- stage z -> bf16 LDS (XOR swizzle: byte ^= (row&7)<<4) + row norms ---
    {
        const int row = tid >> 3, part = tid & 7;
        const f32x4* zr = (const f32x4*)(z + ((size_t)b * 4096 + (size_t)(t0 + row)) * 512);
        f32x4 v[16];
        #pragma unroll
        for (int i = 0; i < 16; ++i) v[i] = zr[part + 8 * i];   // 16 loads in flight
        float ss = 0.0f;
        #pragma unroll
        for (int i = 0; i < 16; ++i) {
            f32x4 vv = v[i];
            ss += vv.x*vv.x + vv.y*vv.y + vv.z*vv.z + vv.w*vv.w;
            u16x4 h; h[0]=f2bf(vv.x); h[1]=f2bf(vv.y); h[2]=f2bf(vv.z); h[3]=f2bf(vv.w);
            int within = ((part + 8 * i) * 8) ^ ((row & 7) << 4);
            *(u16x4*)(qtile + row * 1024 + within) = h;
        }
        ss += __shfl_xor(ss, 1, 64);
        ss += __shfl_xor(ss, 2, 64);
        ss += __shfl_xor(ss, 4, 64);
        if (part == 0) s_invn[row] = 1.0f / fmaxf(sqrtf(ss), 1e-12f);
    }
    __syncthreads();

    f32x4 acc[2][4];
    #pragma unroll
    for (int tf = 0; tf < 2; ++tf)
        #pragma unroll
        for (int nf = 0; nf < 4; ++nf)
            acc[tf][nf] = 0.0f;

    const int swz = (c & 7) << 4;
    s16x8 abuf[2][2];
    {   // A[0]
        int kw = (0 * 64 + g * 16) ^ swz;
        abuf[0][0] = *(const s16x8*)(qtile + c * 1024 + kw);
        abuf[0][1] = *(const s16x8*)(qtile + (c + 16) * 1024 + kw);
    }

    #pragma unroll
    for (int ks = 0; ks < 16; ++ks) {
        if (ks + 3 < 16) {                      // B prefetch, distance 3
            #pragma unroll
            for (int nf = 0; nf < 4; ++nf)
                bbuf[(ks + 3) % 3][nf] =
                    *(const u16x8*)(kbb + nf * 16 * 512 + (ks + 3) * 32);
        }
        if (ks + 1 < 16) {                      // A prefetch, distance 1
            int kw = ((ks + 1) * 64 + g * 16) ^ swz;
            abuf[(ks + 1) & 1][0] = *(const s16x8*)(qtile + c * 1024 + kw);
            abuf[(ks + 1) & 1][1] = *(const s16x8*)(qtile + (c + 16) * 1024 + kw);
        }
        const s16x8 a0f = abuf[ks & 1][0];
        const s16x8 a1f = abuf[ks & 1][1];
        const s16x8 b0f = __builtin_bit_cast(s16x8, bbuf[ks % 3][0]);
        const s16x8 b1f = __builtin_bit_cast(s16x8, bbuf[ks % 3][1]);
        const s16x8 b2f = __builtin_bit_cast(s16x8, bbuf[ks % 3][2]);
        const s16x8 b3f = __builtin_bit_cast(s16x8, bbuf[ks % 3][3]);
        acc[0][0] = __builtin_amdgcn_mfma_f32_16x16x32_bf16(a0f, b0f, acc[0][0], 0, 0, 0);
        acc[0][1] = __builtin_amdgcn_mfma_f32_16x16x32_bf16(a0f, b1f, acc[0][1], 0, 0, 0);
        acc[0][2] = __builtin_amdgcn_mfma_f32_16x16x32_bf16(a0f, b2f, acc[0][2], 0, 0, 0);
        acc[0][3] = __builtin_amdgcn_mfma_f32_16x16x32_bf16(a0f, b3f, acc[0][3], 0, 0, 0);
        acc[1][0] = __builtin_amdgcn_mfma_f32_16x16x32_bf16(a1f, b0f, acc[1][0], 0, 0, 0);
        acc[1][1] = __builtin_amdgcn_mfma_f32_16x16x32_bf16(a1f, b1f, acc[1][1], 0, 0, 0);
        acc[1][2] = __builtin_amdgcn_mfma_f32_16x16x32_bf16(a1f, b2f, acc[1][2], 0, 0, 0);
        acc[1][3] = __builtin_amdgcn_mfma_f32_16x16x32_bf16(a1f, b3f, acc[1][3], 0, 0, 0);
    }

    // --- epilogue ---
    int   lmv[4];
    float elm[4];
    #pragma unroll
    for (int nf = 0; nf < 4; ++nf) {
        int rr  = w * 64 + nf * 16 + c;
        lmv[nf] = load_lm(lms_raw, rr);
        elm[nf] = __expf(alpha_td * (float)lmv[nf] * (1.0f / 4096.0f));
    }
    float invn[2][4], et[2][4];
    #pragma unroll
    for (int tf = 0; tf < 2; ++tf)
        #pragma unroll
        for (int q = 0; q < 4; ++q) {
            int tl = tf * 16 + g * 4 + q;
            invn[tf][q] = s_invn[tl];
            et[tf][q]   = __expf(-alpha_td * (float)(t0 + tl) * (1.0f / 4096.0f));
        }

    float phi[2][4][4];
    float rsum[2][4];
    #pragma unroll
    for (int tf = 0; tf < 2; ++tf) {
        #pragma unroll
        for (int q = 0; q < 4; ++q) {
            int tg = t0 + tf * 16 + g * 4 + q;
            float s = 0.0f;
            #pragma unroll
            for (int nf = 0; nf < 4; ++nf) {
                float v = acc[tf][nf][q] * invn[tf][q];
                float p;
                if (lmv[nf] < tg) {
                    float c2 = v * v;
                    float p1 = fmaf(0.5f, v, 0.5f);          // (1+C)/2
                    float p2 = fmaf(1.5f, c2, -0.5f);        // (3C^2-1)/2
                    float p3 = v * fmaf(2.5f, c2, -1.5f);    // (5C^3-3C)/2
                    p = (sa0 * p1 + sa1 * p2 + sa2 * p3) * (et[tf][q] * elm[nf]);
                } else {
                    p = C0;
                }
                phi[tf][nf][q] = p;
                s += p;
            }
            rsum[tf][q] = s;
        }
    }

    // row sums: reduce across the 16 c-lanes, then across waves via LDS
    #pragma unroll
    for (int tf = 0; tf < 2; ++tf)
        #pragma unroll
        for (int q = 0; q < 4; ++q) {
            float s = rsum[tf][q];
            s += __shfl_xor(s, 1, 64);
            s += __shfl_xor(s, 2, 64);
            s += __shfl_xor(s, 4, 64);
            s += __shfl_xor(s, 8, 64);
            rsum[tf][q] = s;
        }
    if (c == 0) {
        #pragma unroll
        for (int tf = 0; tf < 2; ++tf)
            #pragma unroll
            for (int q = 0; q < 4; ++q)
                s_rs[w][tf * 16 + g * 4 + q] = rsum[tf][q];
    }
    __syncthreads();
    if (tid < 32) {
        float s = s_rs[0][tid] + s_rs[1][tid] + s_rs[2][tid] + s_rs[3][tid];
        s_rsi[tid] = 1.0f / fmaxf(s, 1e-6f);
    }
    __syncthreads();

    // normalize + f32 stores
    #pragma unroll
    for (int tf = 0; tf < 2; ++tf)
        #pragma unroll
        for (int q = 0; q < 4; ++q) {
            int tl = tf * 16 + g * 4 + q;
            float ri = s_rsi[tl];
            size_t obase = ((size_t)b * 4096 + (size_t)(t0 + tl)) * 257
                         + (size_t)(w * 64 + c);
            #pragma unroll
            for (int nf = 0; nf < 4; ++nf)
                out[obase + nf * 16] = phi[tf][nf][q] * ri;
        }
    if (tid < 32)
        out[((size_t)b * 4096 + (size_t)(t0 + tid)) * 257 + 256] = 1.0f;
}

// ---------------------------------------------------------------------------
extern "C" void kernel_launch(void* const* d_in, const int* in_sizes, int n_in,
                              void* d_out, int out_size, void* d_ws, size_t ws_size,
                              hipStream_t stream) {
    const float* z   = (const float*)d_in[0];
    const float* gw  = (const float*)d_in[1];
    const float* ta  = (const float*)d_in[2];
    const void*  lms = (const void*)d_in[3];
    float* out = (float*)d_out;
    unsigned short* kb = (unsigned short*)d_ws;   // 4 MB bf16 K panel

    build_kt<<<16 * 256, 64, 0, stream>>>(z, lms, kb);
    nystrom_mfma<<<16 * 128, 256, 0, stream>>>(z, gw, ta, lms, kb, out);
}

// Round 10
// 68.410 us; speedup vs baseline: 8.3315x; 1.1603x over previous
//
#include <hip/hip_runtime.h>

// Problem: B=16, T=4096, D=512, R=256. Output (B,T,R+1) float32.
// build_kt writes a normalized bf16 K panel in MFMA-fragment-blocked layout;
// nystrom_mfma computes C = Q*K^T via mfma_f32_16x16x32_bf16, fused epilogue.
//
// Panel layout (bytes): kb[b*262144 + w*65536 + (ks*4+nf)*1024 + (c*4+g)*16]
// holds K[w*64+nf*16+c][ks*32+g*8 .. +8) as 8 bf16. One K-loop B-load is a
// contiguous 1KB wave read (16B/lane) -> zero cache-line inflation.

typedef float f32x4 __attribute__((ext_vector_type(4)));
typedef short s16x8 __attribute__((ext_vector_type(8)));
typedef unsigned short u16x4 __attribute__((ext_vector_type(4)));
typedef unsigned short u16x8 __attribute__((ext_vector_type(8)));

// float -> bf16 bits, round-to-nearest-even (finite values only)
__device__ __forceinline__ unsigned short f2bf(float f) {
    unsigned u = __builtin_bit_cast(unsigned, f);
    return (unsigned short)((u + 0x7FFFu + ((u >> 16) & 1u)) >> 16);
}

// landmarks: probe int32 vs int64 layout. linspace(0,4095,256):
// int32 -> word1 == 16 ; int64 little-endian -> word1 == 0.
__device__ __forceinline__ int load_lm(const void* lms_raw, int idx) {
    const int* l32 = (const int*)lms_raw;
    if (l32[1] == 0) {
        const long long* l64 = (const long long*)lms_raw;
        return (int)l64[idx];
    }
    return l32[idx];
}

// softmax(gw) and softplus(ta)
__device__ __forceinline__ void scalars(const float* gw, const float* ta,
                                        float& a0, float& a1, float& a2, float& atd) {
    float w0 = gw[0], w1 = gw[1], w2 = gw[2];
    float wm = fmaxf(w0, fmaxf(w1, w2));
    float e0 = __expf(w0 - wm), e1 = __expf(w1 - wm), e2 = __expf(w2 - wm);
    float einv = 1.0f / (e0 + e1 + e2);
    a0 = e0 * einv; a1 = e1 * einv; a2 = e2 * einv;
    float tv = ta[0];
    atd = (tv > 0.0f) ? (tv + log1pf(__expf(-tv))) : log1pf(__expf(tv));
}

// ---------------------------------------------------------------------------
// Kernel 1: normalized K panel, fragment-blocked. One wave per (b, r).
// Lane L holds k-slice [8L, 8L+8) -> (ks = L>>2, g = L&3).
// ---------------------------------------------------------------------------
__global__ void build_kt(const float* __restrict__ z,
                         const void* __restrict__ lms_raw,
                         unsigned char* __restrict__ kb) {
    const int b = blockIdx.x >> 8;
    const int r = blockIdx.x & 255;
    const int L = threadIdx.x;
    const int lm = load_lm(lms_raw, r);

    const f32x4* zrow = (const f32x4*)(z + ((size_t)b * 4096 + (size_t)lm) * 512);
    f32x4 v0 = zrow[L * 2 + 0];
    f32x4 v1 = zrow[L * 2 + 1];
    float ss = v0.x*v0.x + v0.y*v0.y + v0.z*v0.z + v0.w*v0.w
             + v1.x*v1.x + v1.y*v1.y + v1.z*v1.z + v1.w*v1.w;
    #pragma unroll
    for (int off = 32; off >= 1; off >>= 1) ss += __shfl_xor(ss, off, 64);
    float inv = 1.0f / fmaxf(sqrtf(ss), 1e-12f);

    u16x8 o;
    o[0]=f2bf(v0.x*inv); o[1]=f2bf(v0.y*inv); o[2]=f2bf(v0.z*inv); o[3]=f2bf(v0.w*inv);
    o[4]=f2bf(v1.x*inv); o[5]=f2bf(v1.y*inv); o[6]=f2bf(v1.z*inv); o[7]=f2bf(v1.w*inv);

    const int w  = r >> 6;
    const int nf = (r >> 4) & 3;
    const int c  = r & 15;
    const int ks = L >> 2;
    const int g  = L & 3;
    size_t off = (size_t)b * 262144 + (size_t)w * 65536
               + (size_t)(ks * 4 + nf) * 1024 + (size_t)(c * 4 + g) * 16;
    *(u16x8*)(kb + off) = o;
}

// ---------------------------------------------------------------------------
// Kernel 2: MFMA main. Block = (b, 32 t-rows) x 256 r; 4 waves, wave w owns
// r in [64w, 64w+64). B loads: contiguous 1KB per (ks,nf), base + imm offset.
// B prefetch ring: depth 3, distance 2 ((ks+2)%3 != ks%3 -- no clobber).
// ---------------------------------------------------------------------------
__global__ __launch_bounds__(256, 4) void nystrom_mfma(const float* __restrict__ z,
                                                       const float* __restrict__ gw,
                                                       const float* __restrict__ ta,
                                                       const void* __restrict__ lms_raw,
                                                       const unsigned char* __restrict__ kb,
                                                       float* __restrict__ out) {
    __shared__ unsigned char qtile[32 * 512 * 2];  // 32 KB swizzled bf16 Q tile
    __shared__ float s_invn[32];
    __shared__ float s_rs[4][32];
    __shared__ float s_rsi[32];

    const int tid  = threadIdx.x;
    const int lane = tid & 63;
    const int w    = tid >> 6;                 // wave 0..3
    const int b    = blockIdx.x >> 7;          // 128 blocks per batch
    const int t0   = (blockIdx.x & 127) * 32;

    const int c = lane & 15;   // fragment column
    const int g = lane >> 4;   // k-group / row-group

    float sa0, sa1, sa2, alpha_td;
    scalars(gw, ta, sa0, sa1, sa2, alpha_td);
    const float C0 = 0.5f * (sa0 - sa1);       // Phi at masked positions

    // per-lane B base: fragment-blocked panel, lane offset (c*4+g)*16
    const unsigned char* kbw = kb + (size_t)b * 262144 + (size_t)w * 65536
                             + (size_t)(c * 4 + g) * 16;

    // issue first 2 K-steps' B tiles now; their latency hides under staging
    u16x8 bbuf[3][4];
    #pragma unroll
    for (int p = 0; p < 2; ++p)
        #pragma unroll
        for (int nf = 0; nf < 4; ++nf)
            bbuf[p][nf] = *(const u16x8*)(kbw + (p * 4 + nf) * 1024);

    // --- stage z -> bf16 LDS (XOR swizzle: byte ^= (row&7)<<4) + row norms ---
    {
        const int row = tid >> 3, part = tid & 7;
        const f32x4* zr = (const f32x4*)(z + ((size_t)b * 4096 + (size_t)(t0 + row)) * 512);
        f32x4 v[16];
        #pragma unroll
        for (int i = 0; i < 16; ++i) v[i] = zr[part + 8 * i];
        float ss = 0.0f;
        #pragma unroll
        for (int i = 0; i < 16; ++i) {
            f32x4 vv = v[i];
            ss += vv.x*vv.x + vv.y*vv.y + vv.z*vv.z + vv.w*vv.w;
            u16x4 h; h[0]=f2bf(vv.x); h[1]=f2bf(vv.y); h[2]=f2bf(vv.z); h[3]=f2bf(vv.w);
            int within = ((part + 8 * i) * 8) ^ ((row & 7) << 4);
            *(u16x4*)(qtile + row * 1024 + within) = h;
        }
        ss += __shfl_xor(ss, 1, 64);
        ss += __shfl_xor(ss, 2, 64);
        ss += __shfl_xor(ss, 4, 64);
        if (part == 0) s_invn[row] = 1.0f / fmaxf(sqrtf(ss), 1e-12f);
    }
    __syncthreads();

    f32x4 acc[2][4];
    #pragma unroll
    for (int tf = 0; tf < 2; ++tf)
        #pragma unroll
        for (int nf = 0; nf < 4; ++nf)
            acc[tf][nf] = 0.0f;

    const int swz = (c & 7) << 4;
    s16x8 abuf[2][2];
    {   // A[0]
        int kw = (0 * 64 + g * 16) ^ swz;
        abuf[0][0] = *(const s16x8*)(qtile + c * 1024 + kw);
        abuf[0][1] = *(const s16x8*)(qtile + (c + 16) * 1024 + kw);
    }

    #pragma unroll
    for (int ks = 0; ks < 16; ++ks) {
        if (ks + 2 < 16) {                      // B prefetch, distance 2, ring 3
            #pragma unroll
            for (int nf = 0; nf < 4; ++nf)
                bbuf[(ks + 2) % 3][nf] =
                    *(const u16x8*)(kbw + ((ks + 2) * 4 + nf) * 1024);
        }
        if (ks + 1 < 16) {                      // A prefetch, distance 1
            int kw = ((ks + 1) * 64 + g * 16) ^ swz;
            abuf[(ks + 1) & 1][0] = *(const s16x8*)(qtile + c * 1024 + kw);
            abuf[(ks + 1) & 1][1] = *(const s16x8*)(qtile + (c + 16) * 1024 + kw);
        }
        const s16x8 a0f = abuf[ks & 1][0];
        const s16x8 a1f = abuf[ks & 1][1];
        const s16x8 b0f = __builtin_bit_cast(s16x8, bbuf[ks % 3][0]);
        const s16x8 b1f = __builtin_bit_cast(s16x8, bbuf[ks % 3][1]);
        const s16x8 b2f = __builtin_bit_cast(s16x8, bbuf[ks % 3][2]);
        const s16x8 b3f = __builtin_bit_cast(s16x8, bbuf[ks % 3][3]);
        acc[0][0] = __builtin_amdgcn_mfma_f32_16x16x32_bf16(a0f, b0f, acc[0][0], 0, 0, 0);
        acc[0][1] = __builtin_amdgcn_mfma_f32_16x16x32_bf16(a0f, b1f, acc[0][1], 0, 0, 0);
        acc[0][2] = __builtin_amdgcn_mfma_f32_16x16x32_bf16(a0f, b2f, acc[0][2], 0, 0, 0);
        acc[0][3] = __builtin_amdgcn_mfma_f32_16x16x32_bf16(a0f, b3f, acc[0][3], 0, 0, 0);
        acc[1][0] = __builtin_amdgcn_mfma_f32_16x16x32_bf16(a1f, b0f, acc[1][0], 0, 0, 0);
        acc[1][1] = __builtin_amdgcn_mfma_f32_16x16x32_bf16(a1f, b1f, acc[1][1], 0, 0, 0);
        acc[1][2] = __builtin_amdgcn_mfma_f32_16x16x32_bf16(a1f, b2f, acc[1][2], 0, 0, 0);
        acc[1][3] = __builtin_amdgcn_mfma_f32_16x16x32_bf16(a1f, b3f, acc[1][3], 0, 0, 0);
    }

    // --- epilogue ---
    int   lmv[4];
    float elm[4];
    #pragma unroll
    for (int nf = 0; nf < 4; ++nf) {
        int rr  = w * 64 + nf * 16 + c;
        lmv[nf] = load_lm(lms_raw, rr);
        elm[nf] = __expf(alpha_td * (float)lmv[nf] * (1.0f / 4096.0f));
    }
    float invn[2][4], et[2][4];
    #pragma unroll
    for (int tf = 0; tf < 2; ++tf)
        #pragma unroll
        for (int q = 0; q < 4; ++q) {
            int tl = tf * 16 + g * 4 + q;
            invn[tf][q] = s_invn[tl];
            et[tf][q]   = __expf(-alpha_td * (float)(t0 + tl) * (1.0f / 4096.0f));
        }

    float phi[2][4][4];
    float rsum[2][4];
    #pragma unroll
    for (int tf = 0; tf < 2; ++tf) {
        #pragma unroll
        for (int q = 0; q < 4; ++q) {
            int tg = t0 + tf * 16 + g * 4 + q;
            float s = 0.0f;
            #pragma unroll
            for (int nf = 0; nf < 4; ++nf) {
                float v = acc[tf][nf][q] * invn[tf][q];
                float p;
                if (lmv[nf] < tg) {
                    float c2 = v * v;
                    float p1 = fmaf(0.5f, v, 0.5f);          // (1+C)/2
                    float p2 = fmaf(1.5f, c2, -0.5f);        // (3C^2-1)/2
                    float p3 = v * fmaf(2.5f, c2, -1.5f);    // (5C^3-3C)/2
                    p = (sa0 * p1 + sa1 * p2 + sa2 * p3) * (et[tf][q] * elm[nf]);
                } else {
                    p = C0;
                }
                phi[tf][nf][q] = p;
                s += p;
            }
            rsum[tf][q] = s;
        }
    }

    // row sums: reduce across the 16 c-lanes, then across waves via LDS
    #pragma unroll
    for (int tf = 0; tf < 2; ++tf)
        #pragma unroll
        for (int q = 0; q < 4; ++q) {
            float s = rsum[tf][q];
            s += __shfl_xor(s, 1, 64);
            s += __shfl_xor(s, 2, 64);
            s += __shfl_xor(s, 4, 64);
            s += __shfl_xor(s, 8, 64);
            rsum[tf][q] = s;
        }
    if (c == 0) {
        #pragma unroll
        for (int tf = 0; tf < 2; ++tf)
            #pragma unroll
            for (int q = 0; q < 4; ++q)
                s_rs[w][tf * 16 + g * 4 + q] = rsum[tf][q];
    }
    __syncthreads();
    if (tid < 32) {
        float s = s_rs[0][tid] + s_rs[1][tid] + s_rs[2][tid] + s_rs[3][tid];
        s_rsi[tid] = 1.0f / fmaxf(s, 1e-6f);
    }
    __syncthreads();

    // normalize + f32 stores
    #pragma unroll
    for (int tf = 0; tf < 2; ++tf)
        #pragma unroll
        for (int q = 0; q < 4; ++q) {
            int tl = tf * 16 + g * 4 + q;
            float ri = s_rsi[tl];
            size_t obase = ((size_t)b * 4096 + (size_t)(t0 + tl)) * 257
                         + (size_t)(w * 64 + c);
            #pragma unroll
            for (int nf = 0; nf < 4; ++nf)
                out[obase + nf * 16] = phi[tf][nf][q] * ri;
        }
    if (tid < 32)
        out[((size_t)b * 4096 + (size_t)(t0 + tid)) * 257 + 256] = 1.0f;
}

// ---------------------------------------------------------------------------
extern "C" void kernel_launch(void* const* d_in, const int* in_sizes, int n_in,
                              void* d_out, int out_size, void* d_ws, size_t ws_size,
                              hipStream_t stream) {
    const float* z   = (const float*)d_in[0];
    const float* gw  = (const float*)d_in[1];
    const float* ta  = (const float*)d_in[2];
    const void*  lms = (const void*)d_in[3];
    float* out = (float*)d_out;
    unsigned char* kb = (unsigned char*)d_ws;   // 4 MB fragment-blocked panel

    build_kt<<<16 * 256, 64, 0, stream>>>(z, lms, kb);
    nystrom_mfma<<<16 * 128, 256, 0, stream>>>(z, gw, ta, lms, kb, out);
}

// Round 11
// 60.373 us; speedup vs baseline: 9.4406x; 1.1331x over previous
//
#include <hip/hip_runtime.h>

// Problem: B=16, T=4096, D=512, R=256. Output (B,T,R+1) float32.
// build_kt: normalized bf16 K panel, fragment-blocked [b][ks][rt] 1KB tiles.
//   kb[b*262144 + (ks*16 + rt)*1024 + (c*4+g)*16] = K[rt*16+c][ks*32+g*8 ..+8)
// nystrom_mfma: block = 64 t-rows x 256 r, 8 waves; wave w owns all 64 t x
// r in [32w,32w+32): acc[4][2], 8 MFMA per 2 B-loads (4:1), B-ring depth 4.

typedef float f32x4 __attribute__((ext_vector_type(4)));
typedef short s16x8 __attribute__((ext_vector_type(8)));
typedef unsigned short u16x4 __attribute__((ext_vector_type(4)));
typedef unsigned short u16x8 __attribute__((ext_vector_type(8)));

// float -> bf16 bits, round-to-nearest-even (finite values only)
__device__ __forceinline__ unsigned short f2bf(float f) {
    unsigned u = __builtin_bit_cast(unsigned, f);
    return (unsigned short)((u + 0x7FFFu + ((u >> 16) & 1u)) >> 16);
}

// landmarks: probe int32 vs int64 layout. linspace(0,4095,256):
// int32 -> word1 == 16 ; int64 little-endian -> word1 == 0.
__device__ __forceinline__ int load_lm(const void* lms_raw, int idx) {
    const int* l32 = (const int*)lms_raw;
    if (l32[1] == 0) {
        const long long* l64 = (const long long*)lms_raw;
        return (int)l64[idx];
    }
    return l32[idx];
}

// softmax(gw) and softplus(ta)
__device__ __forceinline__ void scalars(const float* gw, const float* ta,
                                        float& a0, float& a1, float& a2, float& atd) {
    float w0 = gw[0], w1 = gw[1], w2 = gw[2];
    float wm = fmaxf(w0, fmaxf(w1, w2));
    float e0 = __expf(w0 - wm), e1 = __expf(w1 - wm), e2 = __expf(w2 - wm);
    float einv = 1.0f / (e0 + e1 + e2);
    a0 = e0 * einv; a1 = e1 * einv; a2 = e2 * einv;
    float tv = ta[0];
    atd = (tv > 0.0f) ? (tv + log1pf(__expf(-tv))) : log1pf(__expf(tv));
}

// ---------------------------------------------------------------------------
// Kernel 1: normalized K panel, fragment-blocked. One wave per (b, r).
// Lane L holds k-slice [8L, 8L+8) -> (ks = L>>2, g = L&3).
// ---------------------------------------------------------------------------
__global__ void build_kt(const float* __restrict__ z,
                         const void* __restrict__ lms_raw,
                         unsigned char* __restrict__ kb) {
    const int b = blockIdx.x >> 8;
    const int r = blockIdx.x & 255;
    const int L = threadIdx.x;
    const int lm = load_lm(lms_raw, r);

    const f32x4* zrow = (const f32x4*)(z + ((size_t)b * 4096 + (size_t)lm) * 512);
    f32x4 v0 = zrow[L * 2 + 0];
    f32x4 v1 = zrow[L * 2 + 1];
    float ss = v0.x*v0.x + v0.y*v0.y + v0.z*v0.z + v0.w*v0.w
             + v1.x*v1.x + v1.y*v1.y + v1.z*v1.z + v1.w*v1.w;
    #pragma unroll
    for (int off = 32; off >= 1; off >>= 1) ss += __shfl_xor(ss, off, 64);
    float inv = 1.0f / fmaxf(sqrtf(ss), 1e-12f);

    u16x8 o;
    o[0]=f2bf(v0.x*inv); o[1]=f2bf(v0.y*inv); o[2]=f2bf(v0.z*inv); o[3]=f2bf(v0.w*inv);
    o[4]=f2bf(v1.x*inv); o[5]=f2bf(v1.y*inv); o[6]=f2bf(v1.z*inv); o[7]=f2bf(v1.w*inv);

    const int rt = r >> 4;
    const int c  = r & 15;
    const int ks = L >> 2;
    const int g  = L & 3;
    size_t off = (size_t)b * 262144
               + (size_t)(ks * 16 + rt) * 1024 + (size_t)(c * 4 + g) * 16;
    *(u16x8*)(kb + off) = o;
}

// ---------------------------------------------------------------------------
// Kernel 2: MFMA main. Block = (b, 64 t-rows) x 256 r; 8 waves (512 thr).
// Wave w: r in [32w, 32w+32) (rt = 2w, 2w+1), all 64 t (A-frag rows c+16i).
// ---------------------------------------------------------------------------
__global__ __launch_bounds__(512, 4) void nystrom_mfma(const float* __restrict__ z,
                                                       const float* __restrict__ gw,
                                                       const float* __restrict__ ta,
                                                       const void* __restrict__ lms_raw,
                                                       const unsigned char* __restrict__ kb,
                                                       float* __restrict__ out) {
    __shared__ unsigned char qtile[64 * 512 * 2];  // 64 KB swizzled bf16 Q tile
    __shared__ float s_invn[64];
    __shared__ float s_rs[8][64];
    __shared__ float s_rsi[64];

    const int tid  = threadIdx.x;
    const int lane = tid & 63;
    const int w    = tid >> 6;                 // wave 0..7

    // XCD-aware swizzle (1024 blocks, 8 XCDs, 128/XCD): each XCD handles
    // 2 batches -> its private L2 holds only those panels.
    const int wgid = (blockIdx.x & 7) * 128 + (blockIdx.x >> 3);
    const int b    = wgid >> 6;                // 64 t-tiles per batch
    const int t0   = (wgid & 63) * 64;

    const int c = lane & 15;   // fragment column
    const int g = lane >> 4;   // k-group / row-group

    float sa0, sa1, sa2, alpha_td;
    scalars(gw, ta, sa0, sa1, sa2, alpha_td);
    const float C0 = 0.5f * (sa0 - sa1);       // Phi at masked positions

    // per-lane B base (fragment-blocked panel), lane offset (c*4+g)*16
    const unsigned char* kbw = kb + (size_t)b * 262144 + (size_t)(c * 4 + g) * 16;
    const int rt0 = 2 * w;

    // issue first 3 K-steps' B tiles now; latency hides under staging
    u16x8 bbuf[4][2];
    #pragma unroll
    for (int p = 0; p < 3; ++p)
        #pragma unroll
        for (int nf = 0; nf < 2; ++nf)
            bbuf[p][nf] = *(const u16x8*)(kbw + (size_t)(p * 16 + rt0 + nf) * 1024);

    // --- stage z -> bf16 LDS (XOR swizzle: byte ^= (row&7)<<4) + row norms ---
    {
        const int row = tid >> 3, part = tid & 7;   // 64 rows x 8 parts
        const f32x4* zr = (const f32x4*)(z + ((size_t)b * 4096 + (size_t)(t0 + row)) * 512);
        f32x4 v[16];
        #pragma unroll
        for (int i = 0; i < 16; ++i) v[i] = zr[part + 8 * i];
        float ss = 0.0f;
        #pragma unroll
        for (int i = 0; i < 16; ++i) {
            f32x4 vv = v[i];
            ss += vv.x*vv.x + vv.y*vv.y + vv.z*vv.z + vv.w*vv.w;
            u16x4 h; h[0]=f2bf(vv.x); h[1]=f2bf(vv.y); h[2]=f2bf(vv.z); h[3]=f2bf(vv.w);
            int within = ((part + 8 * i) * 8) ^ ((row & 7) << 4);
            *(u16x4*)(qtile + row * 1024 + within) = h;
        }
        ss += __shfl_xor(ss, 1, 64);
        ss += __shfl_xor(ss, 2, 64);
        ss += __shfl_xor(ss, 4, 64);
        if (part == 0) s_invn[row] = 1.0f / fmaxf(sqrtf(ss), 1e-12f);
    }
    __syncthreads();

    f32x4 acc[4][2];
    #pragma unroll
    for (int tf = 0; tf < 4; ++tf)
        #pragma unroll
        for (int nf = 0; nf < 2; ++nf)
            acc[tf][nf] = 0.0f;

    const int swz = (c & 7) << 4;              // (c+16i)&7 == c&7
    s16x8 abuf[2][4];
    {   // A[0]: rows c, c+16, c+32, c+48
        int kw = (0 * 64 + g * 16) ^ swz;
        #pragma unroll
        for (int tf = 0; tf < 4; ++tf)
            abuf[0][tf] = *(const s16x8*)(qtile + (c + 16 * tf) * 1024 + kw);
    }

    #pragma unroll
    for (int ks = 0; ks < 16; ++ks) {
        if (ks + 3 < 16) {                      // B prefetch, distance 3, ring 4
            #pragma unroll
            for (int nf = 0; nf < 2; ++nf)
                bbuf[(ks + 3) & 3][nf] =
                    *(const u16x8*)(kbw + (size_t)((ks + 3) * 16 + rt0 + nf) * 1024);
        }
        if (ks + 1 < 16) {                      // A prefetch, distance 1
            int kw = ((ks + 1) * 64 + g * 16) ^ swz;
            #pragma unroll
            for (int tf = 0; tf < 4; ++tf)
                abuf[(ks + 1) & 1][tf] =
                    *(const s16x8*)(qtile + (c + 16 * tf) * 1024 + kw);
        }
        const s16x8 b0f = __builtin_bit_cast(s16x8, bbuf[ks & 3][0]);
        const s16x8 b1f = __builtin_bit_cast(s16x8, bbuf[ks & 3][1]);
        #pragma unroll
        for (int tf = 0; tf < 4; ++tf) {
            const s16x8 af = abuf[ks & 1][tf];
            acc[tf][0] = __builtin_amdgcn_mfma_f32_16x16x32_bf16(af, b0f, acc[tf][0], 0, 0, 0);
            acc[tf][1] = __builtin_amdgcn_mfma_f32_16x16x32_bf16(af, b1f, acc[tf][1], 0, 0, 0);
        }
    }

    // --- epilogue ---
    int   lmv[2];
    float elm[2];
    #pragma unroll
    for (int nf = 0; nf < 2; ++nf) {
        int rr  = 32 * w + nf * 16 + c;
        lmv[nf] = load_lm(lms_raw, rr);
        elm[nf] = __expf(alpha_td * (float)lmv[nf] * (1.0f / 4096.0f));
    }
    float invn[4][4], et[4][4];
    #pragma unroll
    for (int tf = 0; tf < 4; ++tf)
        #pragma unroll
        for (int q = 0; q < 4; ++q) {
            int tl = tf * 16 + g * 4 + q;
            invn[tf][q] = s_invn[tl];
            et[tf][q]   = __expf(-alpha_td * (float)(t0 + tl) * (1.0f / 4096.0f));
        }

    float phi[4][2][4];
    float rsum[4][4];
    #pragma unroll
    for (int tf = 0; tf < 4; ++tf) {
        #pragma unroll
        for (int q = 0; q < 4; ++q) {
            int tg = t0 + tf * 16 + g * 4 + q;
            float s = 0.0f;
            #pragma unroll
            for (int nf = 0; nf < 2; ++nf) {
                float v = acc[tf][nf][q] * invn[tf][q];
                float p;
                if (lmv[nf] < tg) {
                    float c2 = v * v;
                    float p1 = fmaf(0.5f, v, 0.5f);          // (1+C)/2
                    float p2 = fmaf(1.5f, c2, -0.5f);        // (3C^2-1)/2
                    float p3 = v * fmaf(2.5f, c2, -1.5f);    // (5C^3-3C)/2
                    p = (sa0 * p1 + sa1 * p2 + sa2 * p3) * (et[tf][q] * elm[nf]);
                } else {
                    p = C0;
                }
                phi[tf][nf][q] = p;
                s += p;
            }
            rsum[tf][q] = s;
        }
    }

    // row sums: reduce across the 16 c-lanes (within g-group), then across waves
    #pragma unroll
    for (int tf = 0; tf < 4; ++tf)
        #pragma unroll
        for (int q = 0; q < 4; ++q) {
            float s = rsum[tf][q];
            s += __shfl_xor(s, 1, 64);
            s += __shfl_xor(s, 2, 64);
            s += __shfl_xor(s, 4, 64);
            s += __shfl_xor(s, 8, 64);
            rsum[tf][q] = s;
        }
    if (c == 0) {
        #pragma unroll
        for (int tf = 0; tf < 4; ++tf)
            #pragma unroll
            for (int q = 0; q < 4; ++q)
                s_rs[w][tf * 16 + g * 4 + q] = rsum[tf][q];
    }
    __syncthreads();
    if (tid < 64) {
        float s = 0.0f;
        #pragma unroll
        for (int i = 0; i < 8; ++i) s += s_rs[i][tid];
        s_rsi[tid] = 1.0f / fmaxf(s, 1e-6f);
    }
    __syncthreads();

    // normalize + f32 stores
    #pragma unroll
    for (int tf = 0; tf < 4; ++tf)
        #pragma unroll
        for (int q = 0; q < 4; ++q) {
            int tl = tf * 16 + g * 4 + q;
            float ri = s_rsi[tl];
            size_t obase = ((size_t)b * 4096 + (size_t)(t0 + tl)) * 257
                         + (size_t)(32 * w + c);
            #pragma unroll
            for (int nf = 0; nf < 2; ++nf)
                out[obase + nf * 16] = phi[tf][nf][q] * ri;
        }
    if (tid < 64)
        out[((size_t)b * 4096 + (size_t)(t0 + tid)) * 257 + 256] = 1.0f;
}

// ---------------------------------------------------------------------------
extern "C" void kernel_launch(void* const* d_in, const int* in_sizes, int n_in,
                              void* d_out, int out_size, void* d_ws, size_t ws_size,
                              hipStream_t stream) {
    const float* z   = (const float*)d_in[0];
    const float* gw  = (const float*)d_in[1];
    const float* ta  = (const float*)d_in[2];
    const void*  lms = (const void*)d_in[3];
    float* out = (float*)d_out;
    unsigned char* kb = (unsigned char*)d_ws;   // 4 MB fragment-blocked panel

    build_kt<<<16 * 256, 64, 0, stream>>>(z, lms, kb);
    nystrom_mfma<<<1024, 512, 0, stream>>>(z, gw, ta, lms, kb, out);
}

// Round 12
// 59.599 us; speedup vs baseline: 9.5632x; 1.0130x over previous
//
#include <hip/hip_runtime.h>

// Problem: B=16, T=4096, D=512, R=256. Output (B,T,R+1) float32.
// build_kt: normalized bf16 K panel, fragment-blocked [b][ks][rt] 1KB tiles.
//   kb[b*262144 + (ks*16 + rt)*1024 + (c*4+g)*16] = K[rt*16+c][ks*32+g*8 ..+8)
// nystrom_mfma: block = 64 t-rows x 256 r, 8 waves; wave w owns all 64 t x
// r in [32w,32w+32). K-loop: NAMED-REGISTER B ring (4 slots, distance 4) and
// A ping-pong (distance 1), macro-expanded with literal indices only -- no
// runtime-indexed arrays (previous rounds spilled to scratch: VGPR_Count=56).

typedef float f32x4 __attribute__((ext_vector_type(4)));
typedef short s16x8 __attribute__((ext_vector_type(8)));
typedef unsigned short u16x4 __attribute__((ext_vector_type(4)));
typedef unsigned short u16x8 __attribute__((ext_vector_type(8)));

__device__ __forceinline__ unsigned short f2bf(float f) {
    unsigned u = __builtin_bit_cast(unsigned, f);
    return (unsigned short)((u + 0x7FFFu + ((u >> 16) & 1u)) >> 16);
}

__device__ __forceinline__ int load_lm(const void* lms_raw, int idx) {
    const int* l32 = (const int*)lms_raw;
    if (l32[1] == 0) {
        const long long* l64 = (const long long*)lms_raw;
        return (int)l64[idx];
    }
    return l32[idx];
}

__device__ __forceinline__ void scalars(const float* gw, const float* ta,
                                        float& a0, float& a1, float& a2, float& atd) {
    float w0 = gw[0], w1 = gw[1], w2 = gw[2];
    float wm = fmaxf(w0, fmaxf(w1, w2));
    float e0 = __expf(w0 - wm), e1 = __expf(w1 - wm), e2 = __expf(w2 - wm);
    float einv = 1.0f / (e0 + e1 + e2);
    a0 = e0 * einv; a1 = e1 * einv; a2 = e2 * einv;
    float tv = ta[0];
    atd = (tv > 0.0f) ? (tv + log1pf(__expf(-tv))) : log1pf(__expf(tv));
}

// ---------------------------------------------------------------------------
// Kernel 1: normalized K panel, fragment-blocked. One wave per (b, r).
// ---------------------------------------------------------------------------
__global__ void build_kt(const float* __restrict__ z,
                         const void* __restrict__ lms_raw,
                         unsigned char* __restrict__ kb) {
    const int b = blockIdx.x >> 8;
    const int r = blockIdx.x & 255;
    const int L = threadIdx.x;
    const int lm = load_lm(lms_raw, r);

    const f32x4* zrow = (const f32x4*)(z + ((size_t)b * 4096 + (size_t)lm) * 512);
    f32x4 v0 = zrow[L * 2 + 0];
    f32x4 v1 = zrow[L * 2 + 1];
    float ss = v0.x*v0.x + v0.y*v0.y + v0.z*v0.z + v0.w*v0.w
             + v1.x*v1.x + v1.y*v1.y + v1.z*v1.z + v1.w*v1.w;
    #pragma unroll
    for (int off = 32; off >= 1; off >>= 1) ss += __shfl_xor(ss, off, 64);
    float inv = 1.0f / fmaxf(sqrtf(ss), 1e-12f);

    u16x8 o;
    o[0]=f2bf(v0.x*inv); o[1]=f2bf(v0.y*inv); o[2]=f2bf(v0.z*inv); o[3]=f2bf(v0.w*inv);
    o[4]=f2bf(v1.x*inv); o[5]=f2bf(v1.y*inv); o[6]=f2bf(v1.z*inv); o[7]=f2bf(v1.w*inv);

    const int rt = r >> 4;
    const int c  = r & 15;
    const int ks = L >> 2;
    const int g  = L & 3;
    size_t off = (size_t)b * 262144
               + (size_t)(ks * 16 + rt) * 1024 + (size_t)(c * 4 + g) * 16;
    *(u16x8*)(kb + off) = o;
}

// --- macro-expanded K-loop pieces (all indices literal) ---------------------
#define LDB(S, KS) do { \
    B##S##0 = *(const u16x8*)(kbw + (size_t)((KS) * 16 + rt0 + 0) * 1024); \
    B##S##1 = *(const u16x8*)(kbw + (size_t)((KS) * 16 + rt0 + 1) * 1024); \
} while (0)

#define LDA(AV, KK) do { \
    int kw_ = ((KK) * 64 + g * 16) ^ swz; \
    AV##0 = *(const s16x8*)(qtile + (c     ) * 1024 + kw_); \
    AV##1 = *(const s16x8*)(qtile + (c + 16) * 1024 + kw_); \
    AV##2 = *(const s16x8*)(qtile + (c + 32) * 1024 + kw_); \
    AV##3 = *(const s16x8*)(qtile + (c + 48) * 1024 + kw_); \
} while (0)

#define MM(AV, S) do { \
    s16x8 ba_ = __builtin_bit_cast(s16x8, B##S##0); \
    s16x8 bb_ = __builtin_bit_cast(s16x8, B##S##1); \
    acc00 = __builtin_amdgcn_mfma_f32_16x16x32_bf16(AV##0, ba_, acc00, 0, 0, 0); \
    acc01 = __builtin_amdgcn_mfma_f32_16x16x32_bf16(AV##0, bb_, acc01, 0, 0, 0); \
    acc10 = __builtin_amdgcn_mfma_f32_16x16x32_bf16(AV##1, ba_, acc10, 0, 0, 0); \
    acc11 = __builtin_amdgcn_mfma_f32_16x16x32_bf16(AV##1, bb_, acc11, 0, 0, 0); \
    acc20 = __builtin_amdgcn_mfma_f32_16x16x32_bf16(AV##2, ba_, acc20, 0, 0, 0); \
    acc21 = __builtin_amdgcn_mfma_f32_16x16x32_bf16(AV##2, bb_, acc21, 0, 0, 0); \
    acc30 = __builtin_amdgcn_mfma_f32_16x16x32_bf16(AV##3, ba_, acc30, 0, 0, 0); \
    acc31 = __builtin_amdgcn_mfma_f32_16x16x32_bf16(AV##3, bb_, acc31, 0, 0, 0); \
} while (0)

// step: prefetch next A (LDS), do 8 MFMAs, then reload this B slot (dist 4)
#define STEP(KS, AC, AN, S) do { \
    if ((KS) + 1 < 16) LDA(AN, (KS) + 1); \
    MM(AC, S); \
    if ((KS) + 4 < 16) LDB(S, (KS) + 4); \
} while (0)

// ---------------------------------------------------------------------------
// Kernel 2: MFMA main. Block = (b, 64 t-rows) x 256 r; 8 waves (512 thr).
// ---------------------------------------------------------------------------
__global__ __launch_bounds__(512, 4) void nystrom_mfma(const float* __restrict__ z,
                                                       const float* __restrict__ gw,
                                                       const float* __restrict__ ta,
                                                       const void* __restrict__ lms_raw,
                                                       const unsigned char* __restrict__ kb,
                                                       float* __restrict__ out) {
    __shared__ unsigned char qtile[64 * 512 * 2];  // 64 KB swizzled bf16 Q tile
    __shared__ float s_invn[64];
    __shared__ float s_rs[8][64];
    __shared__ float s_rsi[64];

    const int tid  = threadIdx.x;
    const int lane = tid & 63;
    const int w    = tid >> 6;                 // wave 0..7

    // XCD-aware swizzle (1024 blocks, 8 XCDs): 2 batches per XCD.
    const int wgid = (blockIdx.x & 7) * 128 + (blockIdx.x >> 3);
    const int b    = wgid >> 6;
    const int t0   = (wgid & 63) * 64;

    const int c = lane & 15;
    const int g = lane >> 4;

    float sa0, sa1, sa2, alpha_td;
    scalars(gw, ta, sa0, sa1, sa2, alpha_td);
    const float C0 = 0.5f * (sa0 - sa1);

    const unsigned char* kbw = kb + (size_t)b * 262144 + (size_t)(c * 4 + g) * 16;
    const int rt0 = 2 * w;

    // B ring: 4 named slots x 2 frags; issue ks=0..3 before staging.
    u16x8 B00, B01, B10, B11, B20, B21, B30, B31;
    LDB(0, 0); LDB(1, 1); LDB(2, 2); LDB(3, 3);

    // --- stage z -> bf16 LDS (XOR swizzle) + row norms; 8 loads in flight ---
    {
        const int row = tid >> 3, part = tid & 7;   // 64 rows x 8 parts
        const f32x4* zr = (const f32x4*)(z + ((size_t)b * 4096 + (size_t)(t0 + row)) * 512);
        float ss = 0.0f;
        #pragma unroll
        for (int h = 0; h < 2; ++h) {
            f32x4 v[8];
            #pragma unroll
            for (int i = 0; i < 8; ++i) v[i] = zr[part + 8 * (8 * h + i)];
            #pragma unroll
            for (int i = 0; i < 8; ++i) {
                f32x4 vv = v[i];
                ss += vv.x*vv.x + vv.y*vv.y + vv.z*vv.z + vv.w*vv.w;
                u16x4 hh; hh[0]=f2bf(vv.x); hh[1]=f2bf(vv.y); hh[2]=f2bf(vv.z); hh[3]=f2bf(vv.w);
                int within = ((part + 8 * (8 * h + i)) * 8) ^ ((row & 7) << 4);
                *(u16x4*)(qtile + row * 1024 + within) = hh;
            }
        }
        ss += __shfl_xor(ss, 1, 64);
        ss += __shfl_xor(ss, 2, 64);
        ss += __shfl_xor(ss, 4, 64);
        if (part == 0) s_invn[row] = 1.0f / fmaxf(sqrtf(ss), 1e-12f);
    }
    __syncthreads();

    f32x4 acc00 = {0,0,0,0}, acc01 = {0,0,0,0};
    f32x4 acc10 = {0,0,0,0}, acc11 = {0,0,0,0};
    f32x4 acc20 = {0,0,0,0}, acc21 = {0,0,0,0};
    f32x4 acc30 = {0,0,0,0}, acc31 = {0,0,0,0};

    const int swz = (c & 7) << 4;
    s16x8 A00, A01, A02, A03, A10, A11, A12, A13;
    LDA(A0, 0);

    STEP( 0, A0, A1, 0);  STEP( 1, A1, A0, 1);
    STEP( 2, A0, A1, 2);  STEP( 3, A1, A0, 3);
    STEP( 4, A0, A1, 0);  STEP( 5, A1, A0, 1);
    STEP( 6, A0, A1, 2);  STEP( 7, A1, A0, 3);
    STEP( 8, A0, A1, 0);  STEP( 9, A1, A0, 1);
    STEP(10, A0, A1, 2);  STEP(11, A1, A0, 3);
    STEP(12, A0, A1, 0);  STEP(13, A1, A0, 1);
    STEP(14, A0, A1, 2);  STEP(15, A1, A0, 3);

    // gather named accs into literal-indexed array for the epilogue loops
    f32x4 acc[4][2] = {{acc00, acc01}, {acc10, acc11}, {acc20, acc21}, {acc30, acc31}};

    // --- epilogue ---
    int   lmv[2];
    float elm[2];
    #pragma unroll
    for (int nf = 0; nf < 2; ++nf) {
        int rr  = 32 * w + nf * 16 + c;
        lmv[nf] = load_lm(lms_raw, rr);
        elm[nf] = __expf(alpha_td * (float)lmv[nf] * (1.0f / 4096.0f));
    }
    float eA[4], eB[4];
    #pragma unroll
    for (int tf = 0; tf < 4; ++tf)
        eA[tf] = __expf(-alpha_td * (float)(t0 + tf * 16) * (1.0f / 4096.0f));
    #pragma unroll
    for (int q = 0; q < 4; ++q)
        eB[q] = __expf(-alpha_td * (float)(g * 4 + q) * (1.0f / 4096.0f));
    float invn[4][4];
    #pragma unroll
    for (int tf = 0; tf < 4; ++tf)
        #pragma unroll
        for (int q = 0; q < 4; ++q)
            invn[tf][q] = s_invn[tf * 16 + g * 4 + q];

    float phi[4][2][4];
    float rsum[4][4];
    #pragma unroll
    for (int tf = 0; tf < 4; ++tf) {
        #pragma unroll
        for (int q = 0; q < 4; ++q) {
            int tg = t0 + tf * 16 + g * 4 + q;
            float et = eA[tf] * eB[q];
            float s = 0.0f;
            #pragma unroll
            for (int nf = 0; nf < 2; ++nf) {
                float v = acc[tf][nf][q] * invn[tf][q];
                float p;
                if (lmv[nf] < tg) {
                    float c2 = v * v;
                    float p1 = fmaf(0.5f, v, 0.5f);
                    float p2 = fmaf(1.5f, c2, -0.5f);
                    float p3 = v * fmaf(2.5f, c2, -1.5f);
                    p = (sa0 * p1 + sa1 * p2 + sa2 * p3) * (et * elm[nf]);
                } else {
                    p = C0;
                }
                phi[tf][nf][q] = p;
                s += p;
            }
            rsum[tf][q] = s;
        }
    }

    #pragma unroll
    for (int tf = 0; tf < 4; ++tf)
        #pragma unroll
        for (int q = 0; q < 4; ++q) {
            float s = rsum[tf][q];
            s += __shfl_xor(s, 1, 64);
            s += __shfl_xor(s, 2, 64);
            s += __shfl_xor(s, 4, 64);
            s += __shfl_xor(s, 8, 64);
            rsum[tf][q] = s;
        }
    if (c == 0) {
        #pragma unroll
        for (int tf = 0; tf < 4; ++tf)
            #pragma unroll
            for (int q = 0; q < 4; ++q)
                s_rs[w][tf * 16 + g * 4 + q] = rsum[tf][q];
    }
    __syncthreads();
    if (tid < 64) {
        float s = 0.0f;
        #pragma unroll
        for (int i = 0; i < 8; ++i) s += s_rs[i][tid];
        s_rsi[tid] = 1.0f / fmaxf(s, 1e-6f);
    }
    __syncthreads();

    #pragma unroll
    for (int tf = 0; tf < 4; ++tf)
        #pragma unroll
        for (int q = 0; q < 4; ++q) {
            int tl = tf * 16 + g * 4 + q;
            float ri = s_rsi[tl];
            size_t obase = ((size_t)b * 4096 + (size_t)(t0 + tl)) * 257
                         + (size_t)(32 * w + c);
            #pragma unroll
            for (int nf = 0; nf < 2; ++nf)
                out[obase + nf * 16] = phi[tf][nf][q] * ri;
        }
    if (tid < 64)
        out[((size_t)b * 4096 + (size_t)(t0 + tid)) * 257 + 256] = 1.0f;
}

// ---------------------------------------------------------------------------
extern "C" void kernel_launch(void* const* d_in, const int* in_sizes, int n_in,
                              void* d_out, int out_size, void* d_ws, size_t ws_size,
                              hipStream_t stream) {
    const float* z   = (const float*)d_in[0];
    const float* gw  = (const float*)d_in[1];
    const float* ta  = (const float*)d_in[2];
    const void*  lms = (const void*)d_in[3];
    float* out = (float*)d_out;
    unsigned char* kb = (unsigned char*)d_ws;   // 4 MB fragment-blocked panel

    build_kt<<<16 * 256, 64, 0, stream>>>(z, lms, kb);
    nystrom_mfma<<<1024, 512, 0, stream>>>(z, gw, ta, lms, kb, out);
}